// Round 1
// 7679.963 us; speedup vs baseline: 2.4606x; 2.4606x over previous
//
#include <hip/hip_runtime.h>
#include <cmath>

// Problem constants (from setup_inputs): B=64, S=2048, I=512, H=512
#define BB 64
#define SS 2048
#define II 512
#define HH 512

// ---------------------------------------------------------------------------
// Kernel A: xproj[m][n] = sum_k x[m][k] * Wx[n][k] + bh[n]
// M = B*S = 131072, K = I = 512, N = H = 512. All fp32, NT GEMM.
// (unchanged from previous round — ~1.0 ms, not the bottleneck yet)
// ---------------------------------------------------------------------------
__global__ __launch_bounds__(256) void xproj_kernel(
    const float* __restrict__ A,    // x: (M, 512)
    const float* __restrict__ W,    // Wx: (512, 512) row-major (N x K)
    const float* __restrict__ bias, // bh: (512,)
    float* __restrict__ C)          // out: (M, 512)
{
    __shared__ float Ast[16][68];
    __shared__ float Bst[16][68];

    const int tid = threadIdx.x;
    const long m0 = (long)blockIdx.x * 64;
    const int n0 = blockIdx.y * 64;
    const int row = tid >> 2;
    const int kq = (tid & 3) << 2;
    const int tx = tid & 15;
    const int ty = tid >> 4;

    float acc[4][4] = {};

    for (int k0 = 0; k0 < 512; k0 += 16) {
        float4 a4 = *(const float4*)&A[(m0 + row) * 512 + k0 + kq];
        float4 b4 = *(const float4*)&W[(long)(n0 + row) * 512 + k0 + kq];
        __syncthreads();
        Ast[kq + 0][row] = a4.x; Ast[kq + 1][row] = a4.y;
        Ast[kq + 2][row] = a4.z; Ast[kq + 3][row] = a4.w;
        Bst[kq + 0][row] = b4.x; Bst[kq + 1][row] = b4.y;
        Bst[kq + 2][row] = b4.z; Bst[kq + 3][row] = b4.w;
        __syncthreads();
#pragma unroll
        for (int kk = 0; kk < 16; ++kk) {
            float4 av = *(const float4*)&Ast[kk][ty << 2];
            float4 bv = *(const float4*)&Bst[kk][tx << 2];
            acc[0][0] += av.x * bv.x; acc[0][1] += av.x * bv.y;
            acc[0][2] += av.x * bv.z; acc[0][3] += av.x * bv.w;
            acc[1][0] += av.y * bv.x; acc[1][1] += av.y * bv.y;
            acc[1][2] += av.y * bv.z; acc[1][3] += av.y * bv.w;
            acc[2][0] += av.z * bv.x; acc[2][1] += av.z * bv.y;
            acc[2][2] += av.z * bv.z; acc[2][3] += av.z * bv.w;
            acc[3][0] += av.w * bv.x; acc[3][1] += av.w * bv.y;
            acc[3][2] += av.w * bv.z; acc[3][3] += av.w * bv.w;
        }
    }

    float4 bias4 = *(const float4*)&bias[n0 + (tx << 2)];
#pragma unroll
    for (int a = 0; a < 4; ++a) {
        float4 o;
        o.x = acc[a][0] + bias4.x;
        o.y = acc[a][1] + bias4.y;
        o.z = acc[a][2] + bias4.z;
        o.w = acc[a][3] + bias4.w;
        *(float4*)&C[(m0 + (ty << 2) + a) * 512 + n0 + (tx << 2)] = o;
    }
}

// ---------------------------------------------------------------------------
// Transpose Wh (512x512) -> WhT (coalesced column access).
// ---------------------------------------------------------------------------
__global__ __launch_bounds__(256) void transpose512(
    const float* __restrict__ in, float* __restrict__ out)
{
    __shared__ float tile[32][33];
    int x = blockIdx.x * 32 + threadIdx.x;
    int y = blockIdx.y * 32 + threadIdx.y;
#pragma unroll
    for (int i = 0; i < 32; i += 8)
        tile[threadIdx.y + i][threadIdx.x] = in[(y + i) * 512 + x];
    __syncthreads();
    x = blockIdx.y * 32 + threadIdx.x;
    y = blockIdx.x * 32 + threadIdx.y;
#pragma unroll
    for (int i = 0; i < 32; i += 8)
        out[(y + i) * 512 + x] = tile[threadIdx.x][threadIdx.y + i];
}

// ---------------------------------------------------------------------------
// Persistent cooperative RNN: 4 blocks per batch (j-sliced), Wh slice held
// ENTIRELY in registers (512 thr x 128 VGPR = 256 KB). Eliminates the
// 1 MB-per-step L2 re-stream of Wh that bound the previous kernel.
// h slices exchanged through an LLC-resident double buffer with
// device-scope relaxed atomics + per-wave vmcnt(0) + monotonic flags.
// ---------------------------------------------------------------------------
__global__ __launch_bounds__(512, 2) void rnn_coop(
    float* __restrict__ out,        // (B,S,H): in = xproj+bias, overwritten with h_t
    const float* __restrict__ WhT,  // (512,512) transposed: WhT[k][j] = Wh[j][k]
    const float* __restrict__ h0,   // (B,H)
    float* __restrict__ hlast,      // (B,H)
    float* __restrict__ hbuf,       // [2][B][H] exchange buffer (ws)
    int* __restrict__ flags)        // [B][4] published-step counters (ws, zeroed)
{
    __shared__ float hsh[HH];       // current h for this batch
    __shared__ float psum[512];     // partial-dot reduction

    const int bid = blockIdx.x;
    const int b   = bid >> 2;       // batch
    const int s   = bid & 3;        // j-slice index
    const int j0  = s * 128;
    const int tid = threadIdx.x;
    const int q   = tid >> 7;       // k-quarter 0..3 (wave-uniform)
    const int jl  = tid & 127;      // j within slice
    const int j   = j0 + jl;
    const int kb  = q * 128;

    // Load this thread's Wh fragment into registers (static indexing only):
    // w[kk] = Wh[j][kb+kk] = WhT[(kb+kk)*HH + j]. Coalesced over jl.
    float w[128];
    {
        const float* wsrc = WhT + (long)kb * HH + j;
#pragma unroll
        for (int kk = 0; kk < 128; ++kk)
            w[kk] = wsrc[(long)kk * HH];
    }

    // h_0
    hsh[tid] = h0[b * HH + tid];
    __syncthreads();

    float* po = out + (long)b * SS * HH + j;   // used by tid<128 (jl==tid)
    float xpv = 0.f;
    if (tid < 128) xpv = po[0];                // xp for t=0 (includes bias)

    for (int t = 0; t < SS; ++t) {
        // Prefetch next timestep's xp early; HBM latency hides under FMA+sync.
        float xpn = 0.f;
        if (tid < 128 && t + 1 < SS) xpn = po[(long)(t + 1) * HH];

        // Partial dot over this thread's k-quarter. h reads are wave-uniform
        // LDS broadcasts (ds_read_b128); 4 accumulators break the dep chain.
        float a0 = 0.f, a1 = 0.f, a2 = 0.f, a3 = 0.f;
#pragma unroll
        for (int kk = 0; kk < 128; kk += 4) {
            float4 hv = *(const float4*)&hsh[kb + kk];
            a0 += w[kk + 0] * hv.x;
            a1 += w[kk + 1] * hv.y;
            a2 += w[kk + 2] * hv.z;
            a3 += w[kk + 3] * hv.w;
        }
        psum[tid] = (a0 + a1) + (a2 + a3);
        __syncthreads();

        const int par = (t + 1) & 1;           // publish slot (double buffer)
        if (tid < 128) {
            float v = psum[tid] + psum[tid + 128] + psum[tid + 256] +
                      psum[tid + 384] + xpv;
            float hn = tanhf(v);
            hsh[j0 + tid] = hn;                // own slice locally
            po[(long)t * HH] = hn;             // required output h_t
            __hip_atomic_store(&hbuf[par * (BB * HH) + b * HH + j0 + tid], hn,
                               __ATOMIC_RELAXED, __HIP_MEMORY_SCOPE_AGENT);
        }
        // Per-wave release: each wave drains its own sc1 stores before the
        // barrier; after the barrier the flag store is globally ordered
        // behind ALL waves' h-slice stores.
        asm volatile("s_waitcnt vmcnt(0)" ::: "memory");
        __syncthreads();
        if (tid == 0)
            __hip_atomic_store(&flags[b * 4 + s], t + 1,
                               __ATOMIC_RELAXED, __HIP_MEMORY_SCOPE_AGENT);
        // 3 lanes of wave 0 spin on the group-mates' flags (LLC polls).
        if (tid < 4 && tid != s) {
            while (__hip_atomic_load(&flags[b * 4 + tid],
                                     __ATOMIC_RELAXED,
                                     __HIP_MEMORY_SCOPE_AGENT) < t + 1) {}
        }
        __syncthreads();
        // Gather the 3 foreign slices (384 floats) from the LLC buffer.
        if (tid >= 128) {
            int fj = tid - 128;
            int jg = fj + (fj >= j0 ? 128 : 0);
            hsh[jg] = __hip_atomic_load(&hbuf[par * (BB * HH) + b * HH + jg],
                                        __ATOMIC_RELAXED,
                                        __HIP_MEMORY_SCOPE_AGENT);
        }
        __syncthreads();
        xpv = xpn;
    }

    if (s == 0) hlast[b * HH + tid] = hsh[tid];
}

// ---------------------------------------------------------------------------
// Fallback (previous round's proven kernel) if ws too small or coop launch
// unavailable: sequential recurrence, one block per batch.
// ---------------------------------------------------------------------------
template <bool TRANS>
__global__ __launch_bounds__(512) void rnn_kernel(
    float* __restrict__ out,
    const float* __restrict__ Whx,
    const float* __restrict__ h0,
    float* __restrict__ hlast)
{
    __shared__ float h[HH];
    const int b = blockIdx.x;
    const int j = threadIdx.x;

    h[j] = h0[b * HH + j];
    __syncthreads();

    float* po = out + (long)b * SS * HH + j;

    for (int t = 0; t < SS; ++t) {
        float acc = po[(long)t * HH];
#pragma unroll 4
        for (int k = 0; k < HH; k += 4) {
            float4 hv = *(const float4*)&h[k];
            if (TRANS) {
                acc += Whx[(k + 0) * HH + j] * hv.x;
                acc += Whx[(k + 1) * HH + j] * hv.y;
                acc += Whx[(k + 2) * HH + j] * hv.z;
                acc += Whx[(k + 3) * HH + j] * hv.w;
            } else {
                acc += Whx[j * HH + (k + 0)] * hv.x;
                acc += Whx[j * HH + (k + 1)] * hv.y;
                acc += Whx[j * HH + (k + 2)] * hv.z;
                acc += Whx[j * HH + (k + 3)] * hv.w;
            }
        }
        float hn = tanhf(acc);
        __syncthreads();
        h[j] = hn;
        po[(long)t * HH] = hn;
        __syncthreads();
    }

    hlast[b * HH + j] = h[j];
}

extern "C" void kernel_launch(void* const* d_in, const int* in_sizes, int n_in,
                              void* d_out, int out_size, void* d_ws, size_t ws_size,
                              hipStream_t stream) {
    const float* x  = (const float*)d_in[0];  // (B,S,I)
    const float* h0 = (const float*)d_in[1];  // (B,H)
    const float* Wx = (const float*)d_in[2];  // (H,I)
    const float* Wh = (const float*)d_in[3];  // (H,H)
    const float* bh = (const float*)d_in[4];  // (H,)

    float* out = (float*)d_out;               // (B,S,H) then (B,H) h_last
    float* hlast = out + (long)BB * SS * HH;

    // Kernel A: xproj + bias into the outputs region of d_out.
    dim3 gA(BB * SS / 64, HH / 64);
    xproj_kernel<<<gA, 256, 0, stream>>>(x, Wx, bh, out);

    const size_t whBytes   = (size_t)HH * HH * sizeof(float);      // 1 MB
    const size_t hbufBytes = (size_t)2 * BB * HH * sizeof(float);  // 256 KB
    const size_t flagBytes = (size_t)BB * 4 * sizeof(int);         // 1 KB

    if (ws_size >= whBytes + hbufBytes + flagBytes) {
        float* WhT  = (float*)d_ws;
        float* hbuf = (float*)((char*)d_ws + whBytes);
        int* flags  = (int*)((char*)d_ws + whBytes + hbufBytes);

        transpose512<<<dim3(16, 16), dim3(32, 8), 0, stream>>>(Wh, WhT);
        // Flags must start at 0 each launch (stream-ordered, capture-safe).
        hipMemsetAsync(flags, 0, flagBytes, stream);

        void* args[] = {(void*)&out, (void*)&WhT, (void*)&h0, (void*)&hlast,
                        (void*)&hbuf, (void*)&flags};
        hipError_t ce = hipLaunchCooperativeKernel(
            (const void*)rnn_coop, dim3(BB * 4), dim3(512), args, 0, stream);
        if (ce != hipSuccess) {
            (void)hipGetLastError();  // clear error state
            rnn_kernel<true><<<BB, HH, 0, stream>>>(out, WhT, h0, hlast);
        }
    } else if (ws_size >= whBytes) {
        float* WhT = (float*)d_ws;
        transpose512<<<dim3(16, 16), dim3(32, 8), 0, stream>>>(Wh, WhT);
        rnn_kernel<true><<<BB, HH, 0, stream>>>(out, WhT, h0, hlast);
    } else {
        rnn_kernel<false><<<BB, HH, 0, stream>>>(out, Wh, h0, hlast);
    }
}

// Round 2
// 4997.454 us; speedup vs baseline: 3.7814x; 1.5368x over previous
//
#include <hip/hip_runtime.h>
#include <cmath>

// Problem constants (from setup_inputs): B=64, S=2048, I=512, H=512
#define BB 64
#define SS 2048
#define II 512
#define HH 512

// ---------------------------------------------------------------------------
// Kernel A: xproj[m][n] = sum_k x[m][k] * Wx[n][k] + bh[n]
// M = B*S = 131072, K = I = 512, N = H = 512. All fp32, NT GEMM.
// (~1.1 ms, ~40% of fp32 vector peak — next target after the recurrence)
// ---------------------------------------------------------------------------
__global__ __launch_bounds__(256) void xproj_kernel(
    const float* __restrict__ A,    // x: (M, 512)
    const float* __restrict__ W,    // Wx: (512, 512) row-major (N x K)
    const float* __restrict__ bias, // bh: (512,)
    float* __restrict__ C)          // out: (M, 512)
{
    __shared__ float Ast[16][68];
    __shared__ float Bst[16][68];

    const int tid = threadIdx.x;
    const long m0 = (long)blockIdx.x * 64;
    const int n0 = blockIdx.y * 64;
    const int row = tid >> 2;
    const int kq = (tid & 3) << 2;
    const int tx = tid & 15;
    const int ty = tid >> 4;

    float acc[4][4] = {};

    for (int k0 = 0; k0 < 512; k0 += 16) {
        float4 a4 = *(const float4*)&A[(m0 + row) * 512 + k0 + kq];
        float4 b4 = *(const float4*)&W[(long)(n0 + row) * 512 + k0 + kq];
        __syncthreads();
        Ast[kq + 0][row] = a4.x; Ast[kq + 1][row] = a4.y;
        Ast[kq + 2][row] = a4.z; Ast[kq + 3][row] = a4.w;
        Bst[kq + 0][row] = b4.x; Bst[kq + 1][row] = b4.y;
        Bst[kq + 2][row] = b4.z; Bst[kq + 3][row] = b4.w;
        __syncthreads();
#pragma unroll
        for (int kk = 0; kk < 16; ++kk) {
            float4 av = *(const float4*)&Ast[kk][ty << 2];
            float4 bv = *(const float4*)&Bst[kk][tx << 2];
            acc[0][0] += av.x * bv.x; acc[0][1] += av.x * bv.y;
            acc[0][2] += av.x * bv.z; acc[0][3] += av.x * bv.w;
            acc[1][0] += av.y * bv.x; acc[1][1] += av.y * bv.y;
            acc[1][2] += av.y * bv.z; acc[1][3] += av.y * bv.w;
            acc[2][0] += av.z * bv.x; acc[2][1] += av.z * bv.y;
            acc[2][2] += av.z * bv.z; acc[2][3] += av.z * bv.w;
            acc[3][0] += av.w * bv.x; acc[3][1] += av.w * bv.y;
            acc[3][2] += av.w * bv.z; acc[3][3] += av.w * bv.w;
        }
    }

    float4 bias4 = *(const float4*)&bias[n0 + (tx << 2)];
#pragma unroll
    for (int a = 0; a < 4; ++a) {
        float4 o;
        o.x = acc[a][0] + bias4.x;
        o.y = acc[a][1] + bias4.y;
        o.z = acc[a][2] + bias4.z;
        o.w = acc[a][3] + bias4.w;
        *(float4*)&C[(m0 + (ty << 2) + a) * 512 + n0 + (tx << 2)] = o;
    }
}

// ---------------------------------------------------------------------------
// Transpose Wh (512x512) -> WhT (coalesced column access).
// ---------------------------------------------------------------------------
__global__ __launch_bounds__(256) void transpose512(
    const float* __restrict__ in, float* __restrict__ out)
{
    __shared__ float tile[32][33];
    int x = blockIdx.x * 32 + threadIdx.x;
    int y = blockIdx.y * 32 + threadIdx.y;
#pragma unroll
    for (int i = 0; i < 32; i += 8)
        tile[threadIdx.y + i][threadIdx.x] = in[(y + i) * 512 + x];
    __syncthreads();
    x = blockIdx.y * 32 + threadIdx.x;
    y = blockIdx.x * 32 + threadIdx.y;
#pragma unroll
    for (int i = 0; i < 32; i += 8)
        out[(y + i) * 512 + x] = tile[threadIdx.x][threadIdx.y + i];
}

// ---------------------------------------------------------------------------
// Persistent cooperative RNN: 4 blocks per batch (j-sliced).
// v2 changes vs round 1:
//  (1) Wh slice PINNED in registers via opaque asm — round 1's VGPR_Count=88
//      proved the compiler sank the w[] loads back into the t-loop and
//      re-streamed 256 KB/CU/step from L2 (5200 cyc/step). The asm makes the
//      register the value's only source, so it cannot be rematerialized.
//  (2) Exchange protocol: one packed u64 atomic {tag=t+1, value} per element,
//      parity double-buffered. Readers poll the data word directly — one LLC
//      round trip instead of store-drain + flag-publish + flag-poll + gather,
//      and no vmcnt drain / release fence. Race-freedom: slot par is next
//      overwritten with tag t+3, which orders after every peer published its
//      t+2, which orders after that peer consumed this slot's t+1.
// ---------------------------------------------------------------------------
__global__ __launch_bounds__(512, 2) void rnn_coop(
    float* __restrict__ out,        // (B,S,H): in = xproj+bias, overwritten with h_t
    const float* __restrict__ WhT,  // (512,512) transposed: WhT[k][j] = Wh[j][k]
    const float* __restrict__ h0,   // (B,H)
    float* __restrict__ hlast,      // (B,H)
    unsigned long long* __restrict__ hbuf) // [2][B][H] packed {tag,val} (ws, zeroed)
{
    __shared__ float hsh[HH];       // current h for this batch
    __shared__ float psum[512];     // partial-dot reduction

    const int bid = blockIdx.x;
    const int b   = bid >> 2;       // batch
    const int s   = bid & 3;        // j-slice index
    const int j0  = s * 128;
    const int tid = threadIdx.x;
    const int q   = tid >> 7;       // k-quarter 0..3 (wave-uniform)
    const int jl  = tid & 127;      // j within slice
    const int j   = j0 + jl;
    const int kb  = q * 128;

    // Load this thread's Wh fragment: w[kk] = Wh[j][kb+kk] = WhT[(kb+kk)*HH+j].
    float w[128];
    {
        const float* wsrc = WhT + (long)kb * HH + j;
#pragma unroll
        for (int kk = 0; kk < 128; ++kk)
            w[kk] = wsrc[(long)kk * HH];
    }
    // PIN: make each w[kk] register-resident; the asm is now the value's
    // source, so the loads above cannot be sunk into the t-loop.
#pragma unroll
    for (int kk = 0; kk < 128; ++kk)
        asm volatile("" : "+v"(w[kk]));

    // h_0
    hsh[tid] = h0[b * HH + tid];
    __syncthreads();

    float* po = out + (long)b * SS * HH + j;   // used by tid<128 (jl==tid)
    float xpv = 0.f;
    if (tid < 128) xpv = po[0];                // xp for t=0 (includes bias)

    for (int t = 0; t < SS; ++t) {
        // Prefetch next timestep's xp early; HBM latency hides under the step.
        float xpn = 0.f;
        if (tid < 128 && t + 1 < SS) xpn = po[(long)(t + 1) * HH];

        // Partial dot over this thread's k-quarter. h reads are wave-uniform
        // LDS broadcasts; 4 accumulators break the dep chain.
        float a0 = 0.f, a1 = 0.f, a2 = 0.f, a3 = 0.f;
#pragma unroll
        for (int kk = 0; kk < 128; kk += 4) {
            float4 hv = *(const float4*)&hsh[kb + kk];
            a0 += w[kk + 0] * hv.x;
            a1 += w[kk + 1] * hv.y;
            a2 += w[kk + 2] * hv.z;
            a3 += w[kk + 3] * hv.w;
        }
        psum[tid] = (a0 + a1) + (a2 + a3);
        __syncthreads();   // psum ready; also: all hsh reads of step t done

        const int par = (t + 1) & 1;           // publish/gather slot
        unsigned long long* slot = hbuf + (long)par * (BB * HH) + b * HH;

        if (tid < 128) {
            float v = psum[tid] + psum[tid + 128] + psum[tid + 256] +
                      psum[tid + 384] + xpv;
            float hn = tanhf(v);
            hsh[j0 + tid] = hn;                // own slice locally
            po[(long)t * HH] = hn;             // required output h_t
            unsigned long long pk =
                ((unsigned long long)(unsigned)(t + 1) << 32) |
                (unsigned long long)__float_as_uint(hn);
            __hip_atomic_store(&slot[j0 + tid], pk,
                               __ATOMIC_RELAXED, __HIP_MEMORY_SCOPE_AGENT);
        } else {
            // 384 threads gather exactly the 384 foreign h values by polling
            // the packed word until its tag matches this step.
            int fj = tid - 128;
            int jg = fj + (fj >= j0 ? 128 : 0);
            unsigned long long pk;
            do {
                pk = __hip_atomic_load(&slot[jg], __ATOMIC_RELAXED,
                                       __HIP_MEMORY_SCOPE_AGENT);
            } while ((int)(pk >> 32) != t + 1);
            hsh[jg] = __uint_as_float((unsigned)pk);
        }
        __syncthreads();   // hsh fully updated (own + foreign) for step t+1
        xpv = xpn;
    }

    if (s == 0) hlast[b * HH + tid] = hsh[tid];
}

// ---------------------------------------------------------------------------
// Fallback (round-0 proven kernel) if ws too small or coop launch fails.
// ---------------------------------------------------------------------------
template <bool TRANS>
__global__ __launch_bounds__(512) void rnn_kernel(
    float* __restrict__ out,
    const float* __restrict__ Whx,
    const float* __restrict__ h0,
    float* __restrict__ hlast)
{
    __shared__ float h[HH];
    const int b = blockIdx.x;
    const int j = threadIdx.x;

    h[j] = h0[b * HH + j];
    __syncthreads();

    float* po = out + (long)b * SS * HH + j;

    for (int t = 0; t < SS; ++t) {
        float acc = po[(long)t * HH];
#pragma unroll 4
        for (int k = 0; k < HH; k += 4) {
            float4 hv = *(const float4*)&h[k];
            if (TRANS) {
                acc += Whx[(k + 0) * HH + j] * hv.x;
                acc += Whx[(k + 1) * HH + j] * hv.y;
                acc += Whx[(k + 2) * HH + j] * hv.z;
                acc += Whx[(k + 3) * HH + j] * hv.w;
            } else {
                acc += Whx[j * HH + (k + 0)] * hv.x;
                acc += Whx[j * HH + (k + 1)] * hv.y;
                acc += Whx[j * HH + (k + 2)] * hv.z;
                acc += Whx[j * HH + (k + 3)] * hv.w;
            }
        }
        float hn = tanhf(acc);
        __syncthreads();
        h[j] = hn;
        po[(long)t * HH] = hn;
        __syncthreads();
    }

    hlast[b * HH + j] = h[j];
}

extern "C" void kernel_launch(void* const* d_in, const int* in_sizes, int n_in,
                              void* d_out, int out_size, void* d_ws, size_t ws_size,
                              hipStream_t stream) {
    const float* x  = (const float*)d_in[0];  // (B,S,I)
    const float* h0 = (const float*)d_in[1];  // (B,H)
    const float* Wx = (const float*)d_in[2];  // (H,I)
    const float* Wh = (const float*)d_in[3];  // (H,H)
    const float* bh = (const float*)d_in[4];  // (H,)

    float* out = (float*)d_out;               // (B,S,H) then (B,H) h_last
    float* hlast = out + (long)BB * SS * HH;

    // Kernel A: xproj + bias into the outputs region of d_out.
    dim3 gA(BB * SS / 64, HH / 64);
    xproj_kernel<<<gA, 256, 0, stream>>>(x, Wx, bh, out);

    const size_t whBytes   = (size_t)HH * HH * sizeof(float);              // 1 MB
    const size_t hbufBytes = (size_t)2 * BB * HH * sizeof(unsigned long long); // 512 KB

    if (ws_size >= whBytes + hbufBytes) {
        float* WhT = (float*)d_ws;
        unsigned long long* hbuf = (unsigned long long*)((char*)d_ws + whBytes);

        transpose512<<<dim3(16, 16), dim3(32, 8), 0, stream>>>(Wh, WhT);
        // Tags must start != 1..SS each launch (stream-ordered, capture-safe).
        hipMemsetAsync(hbuf, 0, hbufBytes, stream);

        void* args[] = {(void*)&out, (void*)&WhT, (void*)&h0, (void*)&hlast,
                        (void*)&hbuf};
        hipError_t ce = hipLaunchCooperativeKernel(
            (const void*)rnn_coop, dim3(BB * 4), dim3(512), args, 0, stream);
        if (ce != hipSuccess) {
            (void)hipGetLastError();  // clear error state
            rnn_kernel<true><<<BB, HH, 0, stream>>>(out, WhT, h0, hlast);
        }
    } else if (ws_size >= whBytes) {
        float* WhT = (float*)d_ws;
        transpose512<<<dim3(16, 16), dim3(32, 8), 0, stream>>>(Wh, WhT);
        rnn_kernel<true><<<BB, HH, 0, stream>>>(out, WhT, h0, hlast);
    } else {
        rnn_kernel<false><<<BB, HH, 0, stream>>>(out, Wh, h0, hlast);
    }
}